// Round 9
// baseline (209.754 us; speedup 1.0000x reference)
//
#include <hip/hip_runtime.h>
#include <math.h>

// Problem constants (x: (5,1,256,64,64) f32)
constexpr int NIMG = 5;
constexpr int CCH  = 256;   // channels (both c and d)
constexpr int HWP  = 4096;  // H*W
constexpr int PT   = CCH * HWP;  // elems per image = 1048576

// -----------------------------------------------------------------------------
// LDS-free fully fused kernel. No __shared__, no barriers, no staging.
// Per block: 32 d x 64 p tile, all 5 images. Per thread: 2d x 4p x 5n dual
// accumulators (80 regs). Operand reuse is served by L1/L2:
//   per c-step a block touches 1.25 KB of x + 512 B of w; the XCD swizzle
//   (grid = 64 p-slices x 8 d-tiles; linear wgid%8 == slice%8) pins each
//   p-slice's 8 d-blocks to one XCD -> x slice (2.56 MB/XCD) is L2-resident.
// VMEM issue (~28 cyc/wave-c) and VALU (~164 cyc/wave-c) are separate pipes;
// the LDS pipe (the R1-R8 bottleneck) is idle. VALU-bound by construction.
//   acc_s[n] = sum_c x[n,c,p]*(W1+W2)[c,d]   (wsa = w1+w2 per c: identical
//   acc_2[n] = sum_c x[n,c,p]*W2[c,d]         fp32 chain as passing versions)
//   u = x - acc_s - b ; v = acc_2 ; e=|u[j]-v[i]| ; row-norm threshold;
//   out[i] = sum_j kept_e * x[j].  Epilogue verbatim -> bit-identical output.
// -----------------------------------------------------------------------------
__global__ __launch_bounds__(256, 2) void fused_all(
    const float* __restrict__ x, const float* __restrict__ w,
    const float* __restrict__ bias, float* __restrict__ out)
{
    const int t  = threadIdx.x;
    const int tp = t & 15;                 // p-frag: 4 cols
    const int td = t >> 4;                 // d-frag: 2 rows
    const int p0 = blockIdx.x * 64;        // p-slice (64 cols)
    const int d0 = blockIdx.y * 32;        // d-tile (32 rows)
    const int pl = p0 + tp * 4;            // lane's p base
    const int dl = d0 + td * 2;            // lane's d base

    float acc_s[NIMG][2][4] = {};  // sum_c x*(W1+W2)
    float acc_2[NIMG][2][4] = {};  // sum_c x*W2

    const float* xb  = x + pl;
    const float* wb1 = w + dl;
    const float* wb2 = w + (size_t)CCH * CCH + dl;

    #pragma unroll 4
    for (int c = 0; c < CCH; ++c) {
        const float2 w1v = *reinterpret_cast<const float2*>(wb1 + (size_t)c * CCH);
        const float2 w2v = *reinterpret_cast<const float2*>(wb2 + (size_t)c * CCH);
        const float w2a[2] = {w2v.x, w2v.y};
        const float wsa[2] = {w1v.x + w2v.x, w1v.y + w2v.y};
        #pragma unroll
        for (int n = 0; n < NIMG; ++n) {
            const float4 xv = *reinterpret_cast<const float4*>(
                xb + (size_t)n * PT + (size_t)c * HWP);
            const float xa[4] = {xv.x, xv.y, xv.z, xv.w};
            #pragma unroll
            for (int r = 0; r < 2; ++r) {
                #pragma unroll
                for (int q = 0; q < 4; ++q) {
                    acc_s[n][r][q] = fmaf(wsa[r], xa[q], acc_s[n][r][q]);
                    acc_2[n][r][q] = fmaf(w2a[r], xa[q], acc_2[n][r][q]);
                }
            }
        }
    }

    // ---------------- fused epilogue: edges + threshold + reduce ----------------
    #pragma unroll
    for (int r = 0; r < 2; ++r) {
        const int d = dl + r;
        const float bd = bias[d];
        const size_t base = (size_t)d * HWP + pl;

        float xa[NIMG][4], ua[NIMG][4], va[NIMG][4];
        #pragma unroll
        for (int n = 0; n < NIMG; ++n) {
            const float4 xv = *reinterpret_cast<const float4*>(&x[(size_t)n * PT + base]);
            const float xt[4] = {xv.x, xv.y, xv.z, xv.w};
            #pragma unroll
            for (int q = 0; q < 4; ++q) {
                xa[n][q] = xt[q];
                ua[n][q] = xt[q] - acc_s[n][r][q] - bd;
                va[n][q] = acc_2[n][r][q];
            }
        }

        #pragma unroll
        for (int i = 0; i < NIMG; ++i) {
            float ho[4];
            #pragma unroll
            for (int q = 0; q < 4; ++q) {
                float e[NIMG];
                float sumsq = 0.0f;
                #pragma unroll
                for (int j = 0; j < NIMG; ++j) {
                    e[j] = fabsf(ua[j][q] - va[i][q]);
                    sumsq = fmaf(e[j], e[j], sumsq);
                }
                const float m = fmaxf(sqrtf(sumsq), 1e-12f);
                float h = 0.0f;
                #pragma unroll
                for (int j = 0; j < NIMG; ++j) {
                    const float en = e[j] / m;
                    if (en > 0.35f) h = fmaf(e[j], xa[j][q], h);
                }
                ho[q] = h;
            }
            const float4 ov = {ho[0], ho[1], ho[2], ho[3]};
            *reinterpret_cast<float4*>(&out[(size_t)i * PT + base]) = ov;
        }
    }
}

extern "C" void kernel_launch(void* const* d_in, const int* in_sizes, int n_in,
                              void* d_out, int out_size, void* d_ws, size_t ws_size,
                              hipStream_t stream) {
    const float* x    = (const float*)d_in[0];
    const float* w    = (const float*)d_in[1];
    const float* bias = (const float*)d_in[2];
    float* out = (float*)d_out;

    // grid.x = 64 p-slices, grid.y = 8 d-tiles.
    // Linear wgid = y*64 + x -> wgid % 8 == x % 8: all 8 d-tiles of a p-slice
    // land on the same XCD (round-robin dispatch) -> x slice L2-resident.
    dim3 g(HWP / 64, CCH / 32);   // 64 x 8 = 512 blocks, 2 per CU
    fused_all<<<g, 256, 0, stream>>>(x, w, bias, out);
}